// Round 11
// baseline (1142.445 us; speedup 1.0000x reference)
//
#include <hip/hip_runtime.h>
#include <stdint.h>

#define NNODES 50000
#define D 256
#define NEDGES 800000
#define RREL 8
#define NGRAPHS 64
#define MPAD 50048            // 391 * 128
#define NTILES (MPAD / 128)   // 391
#define SEGS (NNODES*RREL)    // 400000
#define KTOT 2304             // 8*256 + 256
#define KZ 2048
#define KCH (KTOT / 32)       // 72 k-chunks (Bt)
#define ZCH 64                // 64 k-chunks (Z: relations only)
#define CHUNK_E 4096          // 128 rows x 32
#define TILE_E (KCH * CHUNK_E)   // Bt tile elems
#define ZTILE_E (ZCH * CHUNK_E)  // Z tile elems (262144)
#define EPSLN 1e-5f
#define NB_SCAN ((SEGS + 1023) / 1024)   // 391

typedef float f32x4 __attribute__((ext_vector_type(4)));
typedef short bf16x8 __attribute__((ext_vector_type(8)));

__device__ __forceinline__ float bf2f(unsigned short u) {
    union { unsigned int i; float f; } v; v.i = ((unsigned int)u) << 16; return v.f;
}
__device__ __forceinline__ unsigned short f2bf(float f) {
    union { float f; unsigned int i; } v; v.f = f;
    unsigned int x = v.i;
    unsigned int r = (x + 0x7fffu + ((x >> 16) & 1u)) >> 16;
    return (unsigned short)r;
}
__device__ __forceinline__ void gload_lds16(const void* g, void* l) {
    __builtin_amdgcn_global_load_lds((__attribute__((address_space(1))) void*)g,
                                     (__attribute__((address_space(3))) void*)l, 16, 0, 0);
}

// ---------------- setup kernels ----------------

__global__ void cast_f32_bf16(const float* __restrict__ in, unsigned short* __restrict__ out, int n4) {
    int i = blockIdx.x * 256 + threadIdx.x;
    if (i < n4) {
        float4 f = ((const float4*)in)[i];
        ushort4 u; u.x = f2bf(f.x); u.y = f2bf(f.y); u.z = f2bf(f.z); u.w = f2bf(f.w);
        ((ushort4*)out)[i] = u;
    }
}

__global__ void edge_hist(const int* __restrict__ ei, const int* __restrict__ et, int* __restrict__ counts) {
    int e = blockIdx.x * 256 + threadIdx.x;
    if (e < NEDGES) {
        int dst = ei[NEDGES + e];
        atomicAdd(&counts[dst * RREL + et[e]], 1);
    }
}

__global__ void scan1(const int* __restrict__ counts, int* __restrict__ bsum) {
    __shared__ int s[1024];
    int t = threadIdx.x, b = blockIdx.x;
    int i = b * 1024 + t;
    s[t] = (i < SEGS) ? counts[i] : 0;
    __syncthreads();
    for (int off = 512; off > 0; off >>= 1) { if (t < off) s[t] += s[t + off]; __syncthreads(); }
    if (t == 0) bsum[b] = s[0];
}

__global__ void scan2(const int* __restrict__ bsum, int* __restrict__ boff, int nb) {
    __shared__ int s[512];
    int t = threadIdx.x;
    s[t] = (t < nb) ? bsum[t] : 0;
    __syncthreads();
    for (int off = 1; off < 512; off <<= 1) {
        int v = (t >= off) ? s[t - off] : 0;
        __syncthreads(); s[t] += v; __syncthreads();
    }
    if (t < nb) boff[t] = s[t] - bsum[t];  // exclusive
}

__global__ void scan3(const int* __restrict__ counts, const int* __restrict__ boff, int* __restrict__ offsets) {
    __shared__ int s[1024];
    int t = threadIdx.x, b = blockIdx.x;
    int i = b * 1024 + t;
    int c = (i < SEGS) ? counts[i] : 0;
    s[t] = c;
    __syncthreads();
    for (int off = 1; off < 1024; off <<= 1) {
        int v = (t >= off) ? s[t - off] : 0;
        __syncthreads(); s[t] += v; __syncthreads();
    }
    if (i < SEGS) offsets[i] = boff[b] + s[t] - c;
    if (i == SEGS - 1) offsets[SEGS] = boff[b] + s[t];
}

__global__ void edge_scatter(const int* __restrict__ ei, const int* __restrict__ et,
                             const int* __restrict__ offsets, int* __restrict__ cursor,
                             int* __restrict__ edge_src) {
    int e = blockIdx.x * 256 + threadIdx.x;
    if (e < NEDGES) {
        int s = ei[e], dst = ei[NEDGES + e];
        int seg = dst * RREL + et[e];
        int pos = offsets[seg] + atomicAdd(&cursor[seg], 1);
        edge_src[pos] = s;
    }
}

// batch is sorted: start[g] = lower_bound(batch, g); start[NGRAPHS] = NNODES
__global__ void batch_bounds(const int* __restrict__ batch, int* __restrict__ start) {
    int g = threadIdx.x;
    if (g > NGRAPHS) return;
    if (g == NGRAPHS) { start[NGRAPHS] = NNODES; return; }
    int lo = 0, hi = NNODES;
    while (lo < hi) {
        int mid = (lo + hi) >> 1;
        if (batch[mid] < g) lo = mid + 1; else hi = mid;
    }
    start[g] = lo;
}

// Bt for ALL 3 layers, tiled+swizzled: [3][2 n-tiles][72 k-chunks][128 rows][32]
__global__ void build_bt3(const float* __restrict__ Wrel, const float* __restrict__ Wroot,
                          unsigned short* __restrict__ Bt) {
    int idx = blockIdx.x * 256 + threadIdx.x;
    if (idx >= 3 * 2 * TILE_E) return;
    int layer = idx / (2 * TILE_E);
    int rem0 = idx % (2 * TILE_E);
    int nt = rem0 / TILE_E;
    int rem = rem0 % TILE_E;
    int kt = rem >> 12;            // /4096
    int rem2 = rem & 4095;
    int row = rem2 >> 5;
    int kkp = rem2 & 31;
    int kk = ((((kkp >> 3) ^ ((row >> 1) & 3)) << 3) | (kkp & 7));
    int n = nt * 128 + row;
    int k = kt * 32 + kk;
    const float* wr = Wrel + (size_t)layer * RREL * D * D;
    const float* wo = Wroot + (size_t)layer * D * D;
    float v = (k < KZ) ? wr[(size_t)k * 256 + n] : wo[(size_t)(k - KZ) * 256 + n];
    Bt[idx] = f2bf(v);
}

// ---------------- per-layer kernels ----------------

// one wave per NODE; writes tiled+swizzled Z rows [2048 relation cols] (R8-verified)
__global__ void aggregate(const unsigned short* __restrict__ xb,
                          const int* __restrict__ offsets,
                          const int* __restrict__ edge_src,
                          unsigned short* __restrict__ Z,   // chunk-local tiled layout
                          int node_base, int nnode) {
    int wid = (blockIdx.x * 256 + threadIdx.x) >> 6;   // local node
    int lane = threadIdx.x & 63;
    if (wid >= nnode) return;
    int node = node_base + wid;
    int tl = wid >> 7, row = wid & 127;
    // logical k = r*256 + lane*4 : chunk = r*8 + (lane>>3); kk-group = (lane>>1)&3 (^ swz); kk&7 = (lane&1)*4
    size_t base = (size_t)tl * ZTILE_E + (size_t)row * 32
                + (((((lane >> 1) & 3) ^ ((row >> 1) & 3)) << 3) | ((lane & 1) << 2));
    int csub = lane >> 3;
    if (node >= NNODES) {
        ushort4 zz = {0, 0, 0, 0};
#pragma unroll
        for (int r = 0; r < RREL; r++)
            *(ushort4*)&Z[base + (size_t)(r * 8 + csub) * CHUNK_E] = zz;
        return;
    }
    int seg0 = node * RREL;
#pragma unroll
    for (int r = 0; r < RREL; r++) {
        int o0 = offsets[seg0 + r], o1 = offsets[seg0 + r + 1];
        float a0 = 0, a1 = 0, a2 = 0, a3 = 0;
        for (int e = o0; e < o1; ++e) {
            int src = edge_src[e];
            ushort4 u = *(const ushort4*)&xb[(size_t)src * D + lane * 4];
            a0 += bf2f(u.x); a1 += bf2f(u.y); a2 += bf2f(u.z); a3 += bf2f(u.w);
        }
        int cnt = o1 - o0;
        float sc = cnt > 0 ? 1.0f / (float)cnt : 0.0f;
        ushort4 o; o.x = f2bf(a0 * sc); o.y = f2bf(a1 * sc); o.z = f2bf(a2 * sc); o.w = f2bf(a3 * sc);
        *(ushort4*)&Z[base + (size_t)(r * 8 + csub) * CHUNK_E] = o;
    }
}

// C[128,256] per block (grid = tiles) = [Z_rel | xb] @ Bt^T  — Z read ONCE.
// 4 waves, 2x2 layout; each wave: 64 rows x (2 x 64) cols => acc[4][8].
// epilogue: +bias +residual(bf16 xb), ReLU, optional LN stats
template<bool STATS>
__global__ __launch_bounds__(256, 2) void rgcn_gemm(
    const unsigned short* __restrict__ Zt,   // [tiles][64][4096] bf16 swizzled (chunk-local)
    const unsigned short* __restrict__ xb,   // [MPAD,256] bf16 (residual + root-part A)
    const unsigned short* __restrict__ Bt,   // [2][72][128][32] bf16 swizzled (this layer)
    const float* __restrict__ bias,          // [256]
    float* __restrict__ out,                 // [NNODES,256] fp32
    double* __restrict__ stats,              // [2]
    int row0)                                 // global row of chunk start
{
    __shared__ __attribute__((aligned(16))) unsigned short As[CHUNK_E];
    __shared__ __attribute__((aligned(16))) unsigned short Bs[2 * CHUNK_E];
    __shared__ float ws1[4], ws2[4];

    int t = threadIdx.x;
    int wid = t >> 6, lane = t & 63;
    int lt = blockIdx.x;                // local M tile
    int waveM = wid >> 1, waveN = wid & 1;

    const unsigned short* za = Zt + (size_t)lt * ZTILE_E;
    int mrow0 = row0 + lt * 128;

    f32x4 zero = {0.f, 0.f, 0.f, 0.f};
    f32x4 acc[4][8];
#pragma unroll
    for (int m = 0; m < 4; m++)
#pragma unroll
        for (int n = 0; n < 8; n++) acc[m][n] = zero;

    int r15 = lane & 15;
    int kg = (lane >> 4) * 8;
    int swz = (((lane >> 4) ^ ((r15 >> 1) & 3)) << 3);
    int arow = waveM * 64 + r15;
    int brow = waveN * 64 + r15;

    for (int kt = 0; kt < KCH; ++kt) {
        if (kt < ZCH) {
            // relation part: swizzled Z chunk
            const unsigned short* ab = za + ((size_t)kt << 12);
            gload_lds16(ab + t * 8, &As[t * 8]);
            gload_lds16(ab + 2048 + t * 8, &As[2048 + t * 8]);
        } else {
            // root part: stage A straight from xb rows (row-major [row][32])
            int kb = (kt - ZCH) << 5;
            gload_lds16(xb + (size_t)(mrow0 + (t >> 2)) * D + kb + (t & 3) * 8, &As[t * 8]);
            gload_lds16(xb + (size_t)(mrow0 + 64 + (t >> 2)) * D + kb + (t & 3) * 8, &As[2048 + t * 8]);
        }
        // both n-halves of Bt for this chunk
        const unsigned short* b0 = Bt + ((size_t)kt << 12);
        const unsigned short* b1 = b0 + TILE_E;
        gload_lds16(b0 + t * 8, &Bs[t * 8]);
        gload_lds16(b0 + 2048 + t * 8, &Bs[2048 + t * 8]);
        gload_lds16(b1 + t * 8, &Bs[4096 + t * 8]);
        gload_lds16(b1 + 2048 + t * 8, &Bs[6144 + t * 8]);
        __syncthreads();

        int ak = (kt < ZCH) ? swz : kg;
        bf16x8 af[4], bfr[8];
#pragma unroll
        for (int m = 0; m < 4; m++)
            af[m] = *(const bf16x8*)&As[((arow + m * 16) << 5) + ak];
#pragma unroll
        for (int n = 0; n < 8; n++) {
            int half = n >> 2;
            int br = brow + (n & 3) * 16;
            bfr[n] = *(const bf16x8*)&Bs[(half << 12) + (br << 5) + swz];
        }
#pragma unroll
        for (int m = 0; m < 4; m++)
#pragma unroll
            for (int n = 0; n < 8; n++)
                acc[m][n] = __builtin_amdgcn_mfma_f32_16x16x32_bf16(af[m], bfr[n], acc[m][n], 0, 0, 0);
        __syncthreads();
    }

    // epilogue: C row = (lane>>4)*4 + reg, col = (n>>2)*128 + waveN*64 + (n&3)*16 + r15
    float ls = 0.f, ls2 = 0.f;
    int rbase = mrow0 + waveM * 64 + ((lane >> 4) << 2);
    int cb = waveN * 64 + r15;
#pragma unroll
    for (int m = 0; m < 4; m++) {
#pragma unroll
        for (int i = 0; i < 4; i++) {
            int grow = rbase + m * 16 + i;
            if (grow < NNODES) {
#pragma unroll
                for (int n = 0; n < 8; n++) {
                    int gcol = ((n >> 2) << 7) + cb + ((n & 3) << 4);
                    float v = acc[m][n][i] + bias[gcol] + bf2f(xb[(size_t)grow * D + gcol]);
                    v = v > 0.f ? v : 0.f;
                    out[(size_t)grow * D + gcol] = v;
                    if (STATS) { ls += v; ls2 += v * v; }
                }
            }
        }
    }
    if (STATS) {
        for (int off = 32; off > 0; off >>= 1) {
            ls += __shfl_down(ls, off, 64);
            ls2 += __shfl_down(ls2, off, 64);
        }
        if (lane == 0) { ws1[wid] = ls; ws2[wid] = ls2; }
        __syncthreads();
        if (t == 0) {
            float s1 = ws1[0] + ws1[1] + ws1[2] + ws1[3];
            float s2 = ws2[0] + ws2[1] + ws2[2] + ws2[3];
            atomicAdd(&stats[0], (double)s1);
            atomicAdd(&stats[1], (double)s2);
        }
    }
}

// graph-LayerNorm over the whole tensor; writes bf16 x-copy only
__global__ void ln_norm(const float* __restrict__ x, unsigned short* __restrict__ xb,
                        const float* __restrict__ w, const float* __restrict__ b,
                        const double* __restrict__ stats) {
    int i = blockIdx.x * 256 + threadIdx.x;   // over NNODES*64 float4s
    if (i >= NNODES * (D / 4)) return;
    const double cntd = (double)NNODES * (double)D;
    double s1 = stats[0], s2 = stats[1];
    double mud = s1 / cntd;
    double vard = s2 / cntd - mud * mud;
    float mu = (float)mud;
    float sd = sqrtf(vard > 0.0 ? (float)vard : 0.0f);
    float inv = 1.0f / (sd + EPSLN);
    int node = i >> 6, c4 = (i & 63) * 4;
    float4 v = *(const float4*)&x[(size_t)node * D + c4];
    float4 wv = *(const float4*)&w[c4];
    float4 bv = *(const float4*)&b[c4];
    float4 o;
    o.x = wv.x * ((v.x - mu) * inv) + bv.x;
    o.y = wv.y * ((v.y - mu) * inv) + bv.y;
    o.z = wv.z * ((v.z - mu) * inv) + bv.z;
    o.w = wv.w * ((v.w - mu) * inv) + bv.w;
    ushort4 u; u.x = f2bf(o.x); u.y = f2bf(o.y); u.z = f2bf(o.z); u.w = f2bf(o.w);
    *(ushort4*)&xb[(size_t)node * D + c4] = u;
}

// ---------------- tail: pool + MLP ----------------

__global__ void pool2(const float* __restrict__ x, const int* __restrict__ start,
                      float* __restrict__ gsum) {
    int g = blockIdx.x, s = blockIdx.y, j = threadIdx.x;
    int n0 = start[g], n1 = start[g + 1];
    int len = n1 - n0;
    if (len <= 0) return;
    int chunk = (len + 7) / 8;
    int a = n0 + s * chunk;
    int b = a + chunk; if (b > n1) b = n1;
    if (a >= b) return;
    float sum = 0.f;
    for (int n = a; n < b; ++n) sum += x[(size_t)n * D + j];
    atomicAdd(&gsum[(size_t)g * D + j], sum);
}

__global__ void mlp(const float* __restrict__ gsum, const int* __restrict__ start,
                    const float* __restrict__ W1, const float* __restrict__ b1,
                    const float* __restrict__ W2, const float* __restrict__ b2,
                    const float* __restrict__ W3, const float* __restrict__ b3,
                    float* __restrict__ out) {
    __shared__ float gb[256], h1[256], h2[256];
    int g = blockIdx.x, j = threadIdx.x;
    int c = start[g + 1] - start[g]; if (c < 1) c = 1;
    gb[j] = gsum[(size_t)g * D + j] / (float)c;
    __syncthreads();
    float a = b1[j];
    for (int k = 0; k < D; k++) a += gb[k] * W1[(size_t)k * D + j];
    h1[j] = a > 0.f ? a : 0.f;
    __syncthreads();
    a = b2[j];
    for (int k = 0; k < D; k++) a += h1[k] * W2[(size_t)k * D + j];
    h2[j] = a > 0.f ? a : 0.f;
    __syncthreads();
    if (j < 4) {
        a = b3[j];
        for (int k = 0; k < D; k++) a += h2[k] * W3[(size_t)k * 4 + j];
        out[g * 4 + j] = a;
    }
}

// ---------------- workspace layout (Z last, chunked adaptively) ----------------

constexpr size_t A256(size_t x) { return (x + 255) & ~(size_t)255; }
constexpr size_t XB_OFF   = 0;
constexpr size_t XC_OFF   = XB_OFF   + A256((size_t)MPAD * D * 2);
constexpr size_t BT_OFF   = XC_OFF   + A256((size_t)MPAD * D * 4);
constexpr size_t CNT_OFF  = BT_OFF   + A256((size_t)3 * 2 * TILE_E * 2);
constexpr size_t CUR_OFF  = CNT_OFF  + A256((size_t)SEGS * 4);
constexpr size_t OFF_OFF  = CUR_OFF  + A256((size_t)SEGS * 4);
constexpr size_t ESRC_OFF = OFF_OFF  + A256((size_t)(SEGS + 1) * 4);
constexpr size_t BSUM_OFF = ESRC_OFF + A256((size_t)NEDGES * 4);
constexpr size_t BOFF_OFF = BSUM_OFF + A256((size_t)512 * 4);
constexpr size_t STAT_OFF = BOFF_OFF + A256((size_t)512 * 4);
constexpr size_t GSUM_OFF = STAT_OFF + 256;
constexpr size_t STRT_OFF = GSUM_OFF + A256((size_t)NGRAPHS * D * 4);
constexpr size_t Z_OFF    = STRT_OFF + A256((size_t)(NGRAPHS + 1) * 4);
constexpr size_t Z_TILE_BYTES = (size_t)ZTILE_E * 2;   // 512 KiB per 128-row tile

extern "C" void kernel_launch(void* const* d_in, const int* in_sizes, int n_in,
                              void* d_out, int out_size, void* d_ws, size_t ws_size,
                              hipStream_t stream) {
    const float* x_in   = (const float*)d_in[0];
    const int*   ei     = (const int*)d_in[1];
    const int*   et     = (const int*)d_in[2];
    const int*   batch  = (const int*)d_in[3];
    const float* W_rel  = (const float*)d_in[4];
    const float* W_root = (const float*)d_in[5];
    const float* b_conv = (const float*)d_in[6];
    const float* ln_w   = (const float*)d_in[7];
    const float* ln_b   = (const float*)d_in[8];
    const float* W1 = (const float*)d_in[9];
    const float* b1 = (const float*)d_in[10];
    const float* W2 = (const float*)d_in[11];
    const float* b2 = (const float*)d_in[12];
    const float* W3 = (const float*)d_in[13];
    const float* b3 = (const float*)d_in[14];
    float* out = (float*)d_out;
    char* ws = (char*)d_ws;

    unsigned short* xb   = (unsigned short*)(ws + XB_OFF);
    float*          xcur = (float*)(ws + XC_OFF);
    unsigned short* Bt   = (unsigned short*)(ws + BT_OFF);
    int* counts   = (int*)(ws + CNT_OFF);
    int* cursor   = (int*)(ws + CUR_OFF);
    int* offsets  = (int*)(ws + OFF_OFF);
    int* edge_src = (int*)(ws + ESRC_OFF);
    int* bsum     = (int*)(ws + BSUM_OFF);
    int* boff     = (int*)(ws + BOFF_OFF);
    double* stats = (double*)(ws + STAT_OFF);
    float* gsum   = (float*)(ws + GSUM_OFF);
    int* startg   = (int*)(ws + STRT_OFF);
    unsigned short* Z = (unsigned short*)(ws + Z_OFF);

    // adaptive chunk size from actual ws_size (constant across calls -> graph-safe)
    int tiles_chunk = 1;
    if (ws_size > Z_OFF + Z_TILE_BYTES) {
        size_t za = (ws_size - Z_OFF) / Z_TILE_BYTES;
        tiles_chunk = (za > (size_t)NTILES) ? NTILES : (int)za;
    }

    // zero scratch that is accumulated into / pad rows read by GEMM
    (void)hipMemsetAsync(counts, 0, (size_t)SEGS * 4, stream);
    (void)hipMemsetAsync(cursor, 0, (size_t)SEGS * 4, stream);
    (void)hipMemsetAsync(stats, 0, 4 * sizeof(double), stream);
    (void)hipMemsetAsync(gsum, 0, (size_t)NGRAPHS * D * 4, stream);
    (void)hipMemsetAsync(xb + (size_t)NNODES * D, 0, (size_t)(MPAD - NNODES) * D * 2, stream);

    // setup: bf16 x, CSR by (dst, rel), graph bounds, all 3 layers' Bt
    cast_f32_bf16<<<(NNODES * 64) / 256, 256, 0, stream>>>(x_in, xb, NNODES * 64);
    edge_hist<<<NEDGES / 256, 256, 0, stream>>>(ei, et, counts);
    scan1<<<NB_SCAN, 1024, 0, stream>>>(counts, bsum);
    scan2<<<1, 512, 0, stream>>>(bsum, boff, NB_SCAN);
    scan3<<<NB_SCAN, 1024, 0, stream>>>(counts, boff, offsets);
    edge_scatter<<<NEDGES / 256, 256, 0, stream>>>(ei, et, offsets, cursor, edge_src);
    batch_bounds<<<1, 128, 0, stream>>>(batch, startg);
    build_bt3<<<(3 * 2 * TILE_E) / 256, 256, 0, stream>>>(W_rel, W_root, Bt);

    for (int i = 0; i < 3; ++i) {
        const unsigned short* Bti = Bt + (size_t)i * 2 * TILE_E;
        for (int t0 = 0; t0 < NTILES; t0 += tiles_chunk) {
            int tiles = (NTILES - t0 < tiles_chunk) ? (NTILES - t0) : tiles_chunk;
            int row0 = t0 * 128;
            int nnode = tiles * 128;
            aggregate<<<nnode / 4, 256, 0, stream>>>(xb, offsets, edge_src, Z, row0, nnode);
            if (i < 2)
                rgcn_gemm<true><<<tiles, 256, 0, stream>>>(Z, xb, Bti, b_conv + i * D, xcur, stats + 2 * i, row0);
            else
                rgcn_gemm<false><<<tiles, 256, 0, stream>>>(Z, xb, Bti, b_conv + i * D, xcur, stats, row0);
        }
        if (i < 2)
            ln_norm<<<(NNODES * 64) / 256, 256, 0, stream>>>(
                xcur, xb, ln_w + i * D, ln_b + i * D, stats + 2 * i);
    }

    dim3 pgrid(NGRAPHS, 8);
    pool2<<<pgrid, 256, 0, stream>>>(xcur, startg, gsum);
    mlp<<<NGRAPHS, 256, 0, stream>>>(gsum, startg, W1, b1, W2, b2, W3, b3, out);
}

// Round 12
// 1056.272 us; speedup vs baseline: 1.0816x; 1.0816x over previous
//
#include <hip/hip_runtime.h>
#include <stdint.h>

#define NNODES 50000
#define D 256
#define NEDGES 800000
#define RREL 8
#define NGRAPHS 64
#define MPAD 50048            // 391 * 128
#define NTILES (MPAD / 128)   // 391
#define SEGS (NNODES*RREL)    // 400000
#define KTOT 2304             // 8*256 + 256
#define KZ 2048
#define KCH (KTOT / 32)       // 72 k-chunks (Bt)
#define ZCH 64                // 64 k-chunks (Z: relations only)
#define CHUNK_E 4096          // 128 rows x 32
#define TILE_E (KCH * CHUNK_E)   // Bt tile elems
#define ZTILE_E (ZCH * CHUNK_E)  // Z tile elems (262144)
#define EPSLN 1e-5f
#define NB_SCAN ((SEGS + 1023) / 1024)   // 391

typedef float f32x4 __attribute__((ext_vector_type(4)));
typedef short bf16x8 __attribute__((ext_vector_type(8)));

__device__ __forceinline__ float bf2f(unsigned short u) {
    union { unsigned int i; float f; } v; v.i = ((unsigned int)u) << 16; return v.f;
}
__device__ __forceinline__ unsigned short f2bf(float f) {
    union { float f; unsigned int i; } v; v.f = f;
    unsigned int x = v.i;
    unsigned int r = (x + 0x7fffu + ((x >> 16) & 1u)) >> 16;
    return (unsigned short)r;
}
__device__ __forceinline__ void gload_lds16(const void* g, void* l) {
    __builtin_amdgcn_global_load_lds((__attribute__((address_space(1))) void*)g,
                                     (__attribute__((address_space(3))) void*)l, 16, 0, 0);
}

// ---------------- setup kernels ----------------

__global__ void cast_f32_bf16(const float* __restrict__ in, unsigned short* __restrict__ out, int n4) {
    int i = blockIdx.x * 256 + threadIdx.x;
    if (i < n4) {
        float4 f = ((const float4*)in)[i];
        ushort4 u; u.x = f2bf(f.x); u.y = f2bf(f.y); u.z = f2bf(f.z); u.w = f2bf(f.w);
        ((ushort4*)out)[i] = u;
    }
}

__global__ void edge_hist(const int* __restrict__ ei, const int* __restrict__ et, int* __restrict__ counts) {
    int e = blockIdx.x * 256 + threadIdx.x;
    if (e < NEDGES) {
        int dst = ei[NEDGES + e];
        atomicAdd(&counts[dst * RREL + et[e]], 1);
    }
}

__global__ void scan1(const int* __restrict__ counts, int* __restrict__ bsum) {
    __shared__ int s[1024];
    int t = threadIdx.x, b = blockIdx.x;
    int i = b * 1024 + t;
    s[t] = (i < SEGS) ? counts[i] : 0;
    __syncthreads();
    for (int off = 512; off > 0; off >>= 1) { if (t < off) s[t] += s[t + off]; __syncthreads(); }
    if (t == 0) bsum[b] = s[0];
}

__global__ void scan2(const int* __restrict__ bsum, int* __restrict__ boff, int nb) {
    __shared__ int s[512];
    int t = threadIdx.x;
    s[t] = (t < nb) ? bsum[t] : 0;
    __syncthreads();
    for (int off = 1; off < 512; off <<= 1) {
        int v = (t >= off) ? s[t - off] : 0;
        __syncthreads(); s[t] += v; __syncthreads();
    }
    if (t < nb) boff[t] = s[t] - bsum[t];  // exclusive
}

__global__ void scan3(const int* __restrict__ counts, const int* __restrict__ boff, int* __restrict__ offsets) {
    __shared__ int s[1024];
    int t = threadIdx.x, b = blockIdx.x;
    int i = b * 1024 + t;
    int c = (i < SEGS) ? counts[i] : 0;
    s[t] = c;
    __syncthreads();
    for (int off = 1; off < 1024; off <<= 1) {
        int v = (t >= off) ? s[t - off] : 0;
        __syncthreads(); s[t] += v; __syncthreads();
    }
    if (i < SEGS) offsets[i] = boff[b] + s[t] - c;
    if (i == SEGS - 1) offsets[SEGS] = boff[b] + s[t];
}

__global__ void edge_scatter(const int* __restrict__ ei, const int* __restrict__ et,
                             const int* __restrict__ offsets, int* __restrict__ cursor,
                             int* __restrict__ edge_src) {
    int e = blockIdx.x * 256 + threadIdx.x;
    if (e < NEDGES) {
        int s = ei[e], dst = ei[NEDGES + e];
        int seg = dst * RREL + et[e];
        int pos = offsets[seg] + atomicAdd(&cursor[seg], 1);
        edge_src[pos] = s;
    }
}

// batch is sorted: start[g] = lower_bound(batch, g); start[NGRAPHS] = NNODES
__global__ void batch_bounds(const int* __restrict__ batch, int* __restrict__ start) {
    int g = threadIdx.x;
    if (g > NGRAPHS) return;
    if (g == NGRAPHS) { start[NGRAPHS] = NNODES; return; }
    int lo = 0, hi = NNODES;
    while (lo < hi) {
        int mid = (lo + hi) >> 1;
        if (batch[mid] < g) lo = mid + 1; else hi = mid;
    }
    start[g] = lo;
}

// Bt for ALL 3 layers, tiled+swizzled: [3][2 n-tiles][72 k-chunks][128 rows][32]
__global__ void build_bt3(const float* __restrict__ Wrel, const float* __restrict__ Wroot,
                          unsigned short* __restrict__ Bt) {
    int idx = blockIdx.x * 256 + threadIdx.x;
    if (idx >= 3 * 2 * TILE_E) return;
    int layer = idx / (2 * TILE_E);
    int rem0 = idx % (2 * TILE_E);
    int nt = rem0 / TILE_E;
    int rem = rem0 % TILE_E;
    int kt = rem >> 12;            // /4096
    int rem2 = rem & 4095;
    int row = rem2 >> 5;
    int kkp = rem2 & 31;
    int kk = ((((kkp >> 3) ^ ((row >> 1) & 3)) << 3) | (kkp & 7));
    int n = nt * 128 + row;
    int k = kt * 32 + kk;
    const float* wr = Wrel + (size_t)layer * RREL * D * D;
    const float* wo = Wroot + (size_t)layer * D * D;
    float v = (k < KZ) ? wr[(size_t)k * 256 + n] : wo[(size_t)(k - KZ) * 256 + n];
    Bt[idx] = f2bf(v);
}

// ---------------- per-layer kernels ----------------

// one wave per NODE; writes tiled+swizzled Z rows [2048 relation cols] (R8-verified)
__global__ void aggregate(const unsigned short* __restrict__ xb,
                          const int* __restrict__ offsets,
                          const int* __restrict__ edge_src,
                          unsigned short* __restrict__ Z,   // chunk-local tiled layout
                          int node_base, int nnode) {
    int wid = (blockIdx.x * 256 + threadIdx.x) >> 6;   // local node
    int lane = threadIdx.x & 63;
    if (wid >= nnode) return;
    int node = node_base + wid;
    int tl = wid >> 7, row = wid & 127;
    // logical k = r*256 + lane*4 : chunk = r*8 + (lane>>3); kk-group = (lane>>1)&3 (^ swz); kk&7 = (lane&1)*4
    size_t base = (size_t)tl * ZTILE_E + (size_t)row * 32
                + (((((lane >> 1) & 3) ^ ((row >> 1) & 3)) << 3) | ((lane & 1) << 2));
    int csub = lane >> 3;
    if (node >= NNODES) {
        ushort4 zz = {0, 0, 0, 0};
#pragma unroll
        for (int r = 0; r < RREL; r++)
            *(ushort4*)&Z[base + (size_t)(r * 8 + csub) * CHUNK_E] = zz;
        return;
    }
    int seg0 = node * RREL;
#pragma unroll
    for (int r = 0; r < RREL; r++) {
        int o0 = offsets[seg0 + r], o1 = offsets[seg0 + r + 1];
        float a0 = 0, a1 = 0, a2 = 0, a3 = 0;
        for (int e = o0; e < o1; ++e) {
            int src = edge_src[e];
            ushort4 u = *(const ushort4*)&xb[(size_t)src * D + lane * 4];
            a0 += bf2f(u.x); a1 += bf2f(u.y); a2 += bf2f(u.z); a3 += bf2f(u.w);
        }
        int cnt = o1 - o0;
        float sc = cnt > 0 ? 1.0f / (float)cnt : 0.0f;
        ushort4 o; o.x = f2bf(a0 * sc); o.y = f2bf(a1 * sc); o.z = f2bf(a2 * sc); o.w = f2bf(a3 * sc);
        *(ushort4*)&Z[base + (size_t)(r * 8 + csub) * CHUNK_E] = o;
    }
}

// C[64,256] per block (grid = (2, tiles)) = [Z_rel | xb] @ Bt^T — Z still read ONCE.
// 4 waves side-by-side in N: wave wid owns cols [wid*64, wid*64+64); acc[4][4] (verified shape).
// epilogue: +bias +residual(bf16 xb), ReLU, optional LN stats
template<bool STATS>
__global__ __launch_bounds__(256, 3) void rgcn_gemm(
    const unsigned short* __restrict__ Zt,   // [tiles][64][128x32] bf16 swizzled (chunk-local)
    const unsigned short* __restrict__ xb,   // [MPAD,256] bf16 (residual + root-part A)
    const unsigned short* __restrict__ Bt,   // [2][72][128][32] bf16 swizzled (this layer)
    const float* __restrict__ bias,          // [256]
    float* __restrict__ out,                 // [NNODES,256] fp32
    double* __restrict__ stats,              // [2]
    int row0)                                 // global row of chunk start
{
    __shared__ __attribute__((aligned(16))) unsigned short As[2048];      // 64 rows x 32
    __shared__ __attribute__((aligned(16))) unsigned short Bs[2 * CHUNK_E]; // both n-halves
    __shared__ float ws1[4], ws2[4];

    int t = threadIdx.x;
    int wid = t >> 6, lane = t & 63;
    int bm = blockIdx.x;                // 0/1: which 64-row half of the 128-row Z tile
    int lt = blockIdx.y;                // local M tile

    const unsigned short* za = Zt + (size_t)lt * ZTILE_E + bm * 2048;
    int mrow0 = row0 + lt * 128 + bm * 64;

    f32x4 zero = {0.f, 0.f, 0.f, 0.f};
    f32x4 acc[4][4];
#pragma unroll
    for (int m = 0; m < 4; m++)
#pragma unroll
        for (int n = 0; n < 4; n++) acc[m][n] = zero;

    int r15 = lane & 15;
    int kg = (lane >> 4) * 8;
    int swz = (((lane >> 4) ^ ((r15 >> 1) & 3)) << 3);
    int brow = (wid & 1) * 64 + r15;    // row within the 128-row Bt half
    int bhalf = wid >> 1;               // which n-half (cols 0-127 vs 128-255)

    for (int kt = 0; kt < KCH; ++kt) {
        if (kt < ZCH) {
            // relation part: 64-row half of the swizzled Z chunk (rows contiguous)
            gload_lds16(za + ((size_t)kt << 12) + t * 8, &As[t * 8]);
        } else {
            // root part: stage A straight from xb rows (row-major [row][32])
            int kb = (kt - ZCH) << 5;
            gload_lds16(xb + (size_t)(mrow0 + (t >> 2)) * D + kb + (t & 3) * 8, &As[t * 8]);
        }
        // both n-halves of Bt for this chunk
        const unsigned short* b0 = Bt + ((size_t)kt << 12);
        const unsigned short* b1 = b0 + TILE_E;
        gload_lds16(b0 + t * 8, &Bs[t * 8]);
        gload_lds16(b0 + 2048 + t * 8, &Bs[2048 + t * 8]);
        gload_lds16(b1 + t * 8, &Bs[4096 + t * 8]);
        gload_lds16(b1 + 2048 + t * 8, &Bs[6144 + t * 8]);
        __syncthreads();

        int ak = (kt < ZCH) ? swz : kg;
        bf16x8 af[4], bfr[4];
#pragma unroll
        for (int m = 0; m < 4; m++)
            af[m] = *(const bf16x8*)&As[((r15 + m * 16) << 5) + ak];
#pragma unroll
        for (int n = 0; n < 4; n++)
            bfr[n] = *(const bf16x8*)&Bs[(bhalf << 12) + ((brow + n * 16) << 5) + swz];
#pragma unroll
        for (int m = 0; m < 4; m++)
#pragma unroll
            for (int n = 0; n < 4; n++)
                acc[m][n] = __builtin_amdgcn_mfma_f32_16x16x32_bf16(af[m], bfr[n], acc[m][n], 0, 0, 0);
        __syncthreads();
    }

    // epilogue: C row = (lane>>4)*4 + reg, col = wid*64 + n*16 + r15
    float ls = 0.f, ls2 = 0.f;
    int rbase = mrow0 + ((lane >> 4) << 2);
    int cb = wid * 64 + r15;
#pragma unroll
    for (int m = 0; m < 4; m++) {
#pragma unroll
        for (int i = 0; i < 4; i++) {
            int grow = rbase + m * 16 + i;
            if (grow < NNODES) {
#pragma unroll
                for (int n = 0; n < 4; n++) {
                    int gcol = cb + n * 16;
                    float v = acc[m][n][i] + bias[gcol] + bf2f(xb[(size_t)grow * D + gcol]);
                    v = v > 0.f ? v : 0.f;
                    out[(size_t)grow * D + gcol] = v;
                    if (STATS) { ls += v; ls2 += v * v; }
                }
            }
        }
    }
    if (STATS) {
        for (int off = 32; off > 0; off >>= 1) {
            ls += __shfl_down(ls, off, 64);
            ls2 += __shfl_down(ls2, off, 64);
        }
        if (lane == 0) { ws1[wid] = ls; ws2[wid] = ls2; }
        __syncthreads();
        if (t == 0) {
            float s1 = ws1[0] + ws1[1] + ws1[2] + ws1[3];
            float s2 = ws2[0] + ws2[1] + ws2[2] + ws2[3];
            atomicAdd(&stats[0], (double)s1);
            atomicAdd(&stats[1], (double)s2);
        }
    }
}

// graph-LayerNorm over the whole tensor; writes bf16 x-copy only
__global__ void ln_norm(const float* __restrict__ x, unsigned short* __restrict__ xb,
                        const float* __restrict__ w, const float* __restrict__ b,
                        const double* __restrict__ stats) {
    int i = blockIdx.x * 256 + threadIdx.x;   // over NNODES*64 float4s
    if (i >= NNODES * (D / 4)) return;
    const double cntd = (double)NNODES * (double)D;
    double s1 = stats[0], s2 = stats[1];
    double mud = s1 / cntd;
    double vard = s2 / cntd - mud * mud;
    float mu = (float)mud;
    float sd = sqrtf(vard > 0.0 ? (float)vard : 0.0f);
    float inv = 1.0f / (sd + EPSLN);
    int node = i >> 6, c4 = (i & 63) * 4;
    float4 v = *(const float4*)&x[(size_t)node * D + c4];
    float4 wv = *(const float4*)&w[c4];
    float4 bv = *(const float4*)&b[c4];
    float4 o;
    o.x = wv.x * ((v.x - mu) * inv) + bv.x;
    o.y = wv.y * ((v.y - mu) * inv) + bv.y;
    o.z = wv.z * ((v.z - mu) * inv) + bv.z;
    o.w = wv.w * ((v.w - mu) * inv) + bv.w;
    ushort4 u; u.x = f2bf(o.x); u.y = f2bf(o.y); u.z = f2bf(o.z); u.w = f2bf(o.w);
    *(ushort4*)&xb[(size_t)node * D + c4] = u;
}

// ---------------- tail: pool + MLP ----------------

__global__ void pool2(const float* __restrict__ x, const int* __restrict__ start,
                      float* __restrict__ gsum) {
    int g = blockIdx.x, s = blockIdx.y, j = threadIdx.x;
    int n0 = start[g], n1 = start[g + 1];
    int len = n1 - n0;
    if (len <= 0) return;
    int chunk = (len + 7) / 8;
    int a = n0 + s * chunk;
    int b = a + chunk; if (b > n1) b = n1;
    if (a >= b) return;
    float sum = 0.f;
    for (int n = a; n < b; ++n) sum += x[(size_t)n * D + j];
    atomicAdd(&gsum[(size_t)g * D + j], sum);
}

__global__ void mlp(const float* __restrict__ gsum, const int* __restrict__ start,
                    const float* __restrict__ W1, const float* __restrict__ b1,
                    const float* __restrict__ W2, const float* __restrict__ b2,
                    const float* __restrict__ W3, const float* __restrict__ b3,
                    float* __restrict__ out) {
    __shared__ float gb[256], h1[256], h2[256];
    int g = blockIdx.x, j = threadIdx.x;
    int c = start[g + 1] - start[g]; if (c < 1) c = 1;
    gb[j] = gsum[(size_t)g * D + j] / (float)c;
    __syncthreads();
    float a = b1[j];
    for (int k = 0; k < D; k++) a += gb[k] * W1[(size_t)k * D + j];
    h1[j] = a > 0.f ? a : 0.f;
    __syncthreads();
    a = b2[j];
    for (int k = 0; k < D; k++) a += h1[k] * W2[(size_t)k * D + j];
    h2[j] = a > 0.f ? a : 0.f;
    __syncthreads();
    if (j < 4) {
        a = b3[j];
        for (int k = 0; k < D; k++) a += h2[k] * W3[(size_t)k * 4 + j];
        out[g * 4 + j] = a;
    }
}

// ---------------- workspace layout (Z last, chunked adaptively) ----------------

constexpr size_t A256(size_t x) { return (x + 255) & ~(size_t)255; }
constexpr size_t XB_OFF   = 0;
constexpr size_t XC_OFF   = XB_OFF   + A256((size_t)MPAD * D * 2);
constexpr size_t BT_OFF   = XC_OFF   + A256((size_t)MPAD * D * 4);
constexpr size_t CNT_OFF  = BT_OFF   + A256((size_t)3 * 2 * TILE_E * 2);
constexpr size_t CUR_OFF  = CNT_OFF  + A256((size_t)SEGS * 4);
constexpr size_t OFF_OFF  = CUR_OFF  + A256((size_t)SEGS * 4);
constexpr size_t ESRC_OFF = OFF_OFF  + A256((size_t)(SEGS + 1) * 4);
constexpr size_t BSUM_OFF = ESRC_OFF + A256((size_t)NEDGES * 4);
constexpr size_t BOFF_OFF = BSUM_OFF + A256((size_t)512 * 4);
constexpr size_t STAT_OFF = BOFF_OFF + A256((size_t)512 * 4);
constexpr size_t GSUM_OFF = STAT_OFF + 256;
constexpr size_t STRT_OFF = GSUM_OFF + A256((size_t)NGRAPHS * D * 4);
constexpr size_t Z_OFF    = STRT_OFF + A256((size_t)(NGRAPHS + 1) * 4);
constexpr size_t Z_TILE_BYTES = (size_t)ZTILE_E * 2;   // 512 KiB per 128-row tile

extern "C" void kernel_launch(void* const* d_in, const int* in_sizes, int n_in,
                              void* d_out, int out_size, void* d_ws, size_t ws_size,
                              hipStream_t stream) {
    const float* x_in   = (const float*)d_in[0];
    const int*   ei     = (const int*)d_in[1];
    const int*   et     = (const int*)d_in[2];
    const int*   batch  = (const int*)d_in[3];
    const float* W_rel  = (const float*)d_in[4];
    const float* W_root = (const float*)d_in[5];
    const float* b_conv = (const float*)d_in[6];
    const float* ln_w   = (const float*)d_in[7];
    const float* ln_b   = (const float*)d_in[8];
    const float* W1 = (const float*)d_in[9];
    const float* b1 = (const float*)d_in[10];
    const float* W2 = (const float*)d_in[11];
    const float* b2 = (const float*)d_in[12];
    const float* W3 = (const float*)d_in[13];
    const float* b3 = (const float*)d_in[14];
    float* out = (float*)d_out;
    char* ws = (char*)d_ws;

    unsigned short* xb   = (unsigned short*)(ws + XB_OFF);
    float*          xcur = (float*)(ws + XC_OFF);
    unsigned short* Bt   = (unsigned short*)(ws + BT_OFF);
    int* counts   = (int*)(ws + CNT_OFF);
    int* cursor   = (int*)(ws + CUR_OFF);
    int* offsets  = (int*)(ws + OFF_OFF);
    int* edge_src = (int*)(ws + ESRC_OFF);
    int* bsum     = (int*)(ws + BSUM_OFF);
    int* boff     = (int*)(ws + BOFF_OFF);
    double* stats = (double*)(ws + STAT_OFF);
    float* gsum   = (float*)(ws + GSUM_OFF);
    int* startg   = (int*)(ws + STRT_OFF);
    unsigned short* Z = (unsigned short*)(ws + Z_OFF);

    // adaptive chunk size from actual ws_size (constant across calls -> graph-safe)
    int tiles_chunk = 1;
    if (ws_size > Z_OFF + Z_TILE_BYTES) {
        size_t za = (ws_size - Z_OFF) / Z_TILE_BYTES;
        tiles_chunk = (za > (size_t)NTILES) ? NTILES : (int)za;
    }

    // zero scratch that is accumulated into / pad rows read by GEMM
    (void)hipMemsetAsync(counts, 0, (size_t)SEGS * 4, stream);
    (void)hipMemsetAsync(cursor, 0, (size_t)SEGS * 4, stream);
    (void)hipMemsetAsync(stats, 0, 4 * sizeof(double), stream);
    (void)hipMemsetAsync(gsum, 0, (size_t)NGRAPHS * D * 4, stream);
    (void)hipMemsetAsync(xb + (size_t)NNODES * D, 0, (size_t)(MPAD - NNODES) * D * 2, stream);

    // setup: bf16 x, CSR by (dst, rel), graph bounds, all 3 layers' Bt
    cast_f32_bf16<<<(NNODES * 64) / 256, 256, 0, stream>>>(x_in, xb, NNODES * 64);
    edge_hist<<<NEDGES / 256, 256, 0, stream>>>(ei, et, counts);
    scan1<<<NB_SCAN, 1024, 0, stream>>>(counts, bsum);
    scan2<<<1, 512, 0, stream>>>(bsum, boff, NB_SCAN);
    scan3<<<NB_SCAN, 1024, 0, stream>>>(counts, boff, offsets);
    edge_scatter<<<NEDGES / 256, 256, 0, stream>>>(ei, et, offsets, cursor, edge_src);
    batch_bounds<<<1, 128, 0, stream>>>(batch, startg);
    build_bt3<<<(3 * 2 * TILE_E) / 256, 256, 0, stream>>>(W_rel, W_root, Bt);

    for (int i = 0; i < 3; ++i) {
        const unsigned short* Bti = Bt + (size_t)i * 2 * TILE_E;
        for (int t0 = 0; t0 < NTILES; t0 += tiles_chunk) {
            int tiles = (NTILES - t0 < tiles_chunk) ? (NTILES - t0) : tiles_chunk;
            int row0 = t0 * 128;
            int nnode = tiles * 128;
            aggregate<<<nnode / 4, 256, 0, stream>>>(xb, offsets, edge_src, Z, row0, nnode);
            dim3 ggrid(2, tiles);
            if (i < 2)
                rgcn_gemm<true><<<ggrid, 256, 0, stream>>>(Z, xb, Bti, b_conv + i * D, xcur, stats + 2 * i, row0);
            else
                rgcn_gemm<false><<<ggrid, 256, 0, stream>>>(Z, xb, Bti, b_conv + i * D, xcur, stats, row0);
        }
        if (i < 2)
            ln_norm<<<(NNODES * 64) / 256, 256, 0, stream>>>(
                xcur, xb, ln_w + i * D, ln_b + i * D, stats + 2 * i);
    }

    dim3 pgrid(NGRAPHS, 8);
    pool2<<<pgrid, 256, 0, stream>>>(xcur, startg, gsum);
    mlp<<<NGRAPHS, 256, 0, stream>>>(gsum, startg, W1, b1, W2, b2, W3, b3, out);
}